// Round 1
// baseline (4753.508 us; speedup 1.0000x reference)
//
#include <hip/hip_runtime.h>

#define NN 100000
#define EE 640000
#define DD 128
#define RR 8

typedef __attribute__((ext_vector_type(8))) short short8;
typedef __attribute__((ext_vector_type(4))) float floatx4;

__device__ __forceinline__ unsigned short f2bf(float f) {
  unsigned int u = __float_as_uint(f);
  u += 0x7FFFu + ((u >> 16) & 1u);   // round-to-nearest-even
  return (unsigned short)(u >> 16);
}

// ---------------------------------------------------------------------------
// Bucket edges by relation (wave-aggregated append) + per-(rel,dst) counts
// ---------------------------------------------------------------------------
__global__ __launch_bounds__(256) void bucket_kernel(
    const int* __restrict__ ei, const int* __restrict__ et,
    int2* __restrict__ ebuf, int* __restrict__ bcnt, float* __restrict__ cnt)
{
  int e = blockIdx.x * 256 + threadIdx.x;
  int t = (e < EE) ? et[e] : -1;
  int lane = threadIdx.x & 63;
  unsigned long long lanebit = 1ull << lane;
  int src = 0, dst = 0;
  if (e < EE) { src = ei[e]; dst = ei[EE + e]; }
  for (int r = 0; r < RR; ++r) {
    unsigned long long m = __ballot(t == r);
    if (t == r) {
      int rank = (int)__popcll(m & (lanebit - 1ull));
      int leader = (int)__ffsll((unsigned long long)m) - 1;
      int base = 0;
      if (lane == leader) base = atomicAdd(&bcnt[r], (int)__popcll(m));
      base = __shfl(base, leader, 64);
      ebuf[(size_t)r * EE + base + rank] = make_int2(src, dst);
      atomicAdd(&cnt[(size_t)r * NN + dst], 1.0f);
    }
  }
}

// ---------------------------------------------------------------------------
// Scatter-add X[src] rows into agg[dst] for one relation. 32 lanes per edge,
// float4 gather + 4 fp32 atomics per lane.
// ---------------------------------------------------------------------------
__global__ __launch_bounds__(256) void scatter_kernel(
    const int2* __restrict__ ebuf, const int* __restrict__ bcnt, int r,
    const float4* __restrict__ X, float* agg)
{
  int n = bcnt[r];
  const int2* e = ebuf + (size_t)r * EE;
  int g = (blockIdx.x * 256 + threadIdx.x) >> 5;
  int lane = threadIdx.x & 31;
  int stride = (gridDim.x * 256) >> 5;
  for (int i = g; i < n; i += stride) {
    int2 ed = e[i];
    float4 v = X[(size_t)ed.x * 32 + lane];
    float* d = agg + (size_t)ed.y * DD + lane * 4;
    atomicAdd(d + 0, v.x);
    atomicAdd(d + 1, v.y);
    atomicAdd(d + 2, v.z);
    atomicAdd(d + 3, v.w);
  }
}

// ---------------------------------------------------------------------------
// GEMM pass: out[128-row tile] (+)= (A * rowscale) @ W  (+bias) (relu)
// BM=128, BN=128, K=128 (whole). bf16 MFMA 16x16x32, 4 waves = 2x2 quadrants.
// XOR-swizzled LDS (16B chunk granularity), exactly 64KB LDS.
// flags: 1=accumulate into out, 2=relu, 4=zero A region after reading.
// ---------------------------------------------------------------------------
__global__ __launch_bounds__(256, 2) void gemm_pass(
    const float* A, float* Azero,
    const float* scale,                // per-row count (or null): s = 1/max(c,1)
    const float* __restrict__ W,       // [K=128][N=128] row-major f32
    const float* __restrict__ bias,    // [128] or null
    float* out, int flags)
{
  __shared__ unsigned short As[128][128];
  __shared__ unsigned short Ws[128][128];
  const int tid = threadIdx.x;
  const int row0 = blockIdx.x * 128;

  // ---- stage A (f32 -> bf16, scaled, swizzled) ----
  {
    int row = tid >> 1, half = tid & 1;
    int grow = row0 + row;
    float s = 1.0f;
    if (scale != nullptr && grow < NN) s = 1.0f / fmaxf(scale[grow], 1.0f);
    const float4* A4 = (const float4*)A;
#pragma unroll
    for (int i = 0; i < 8; ++i) {
      int c = half * 8 + i;  // 16B chunk index (8 bf16)
      float4 v0 = make_float4(0.f, 0.f, 0.f, 0.f), v1 = v0;
      if (grow < NN) {
        v0 = A4[(size_t)grow * 32 + c * 2];
        v1 = A4[(size_t)grow * 32 + c * 2 + 1];
      }
      short8 pk;
      pk[0] = (short)f2bf(v0.x * s); pk[1] = (short)f2bf(v0.y * s);
      pk[2] = (short)f2bf(v0.z * s); pk[3] = (short)f2bf(v0.w * s);
      pk[4] = (short)f2bf(v1.x * s); pk[5] = (short)f2bf(v1.y * s);
      pk[6] = (short)f2bf(v1.z * s); pk[7] = (short)f2bf(v1.w * s);
      int cs = c ^ (row & 15);
      *(short8*)&As[row][cs * 8] = pk;
    }
    if ((flags & 4) && grow < NN) {
      float4* Az = (float4*)Azero;
      float4 z = make_float4(0.f, 0.f, 0.f, 0.f);
#pragma unroll
      for (int i = 0; i < 16; ++i) Az[(size_t)grow * 32 + half * 16 + i] = z;
    }
  }

  // ---- stage W transposed: Ws[n][k] (f32 -> bf16, swizzled) ----
  {
    int n = tid >> 1, khalf = tid & 1;
#pragma unroll
    for (int ci = 0; ci < 8; ++ci) {
      short8 pk;
#pragma unroll
      for (int j = 0; j < 8; ++j) {
        int k = khalf * 64 + ci * 8 + j;
        pk[j] = (short)f2bf(W[k * DD + n]);
      }
      int c = khalf * 8 + ci;
      int cs = c ^ (n & 15);
      *(short8*)&Ws[n][cs * 8] = pk;
    }
  }
  __syncthreads();

  // ---- compute: each wave a 64x64 quadrant ----
  const int wave = tid >> 6, lane = tid & 63;
  const int quad = lane >> 4, mr = lane & 15;
  const int wm = wave >> 1, wn = wave & 1;

  floatx4 acc[4][4];
#pragma unroll
  for (int mi = 0; mi < 4; ++mi)
#pragma unroll
    for (int ni = 0; ni < 4; ++ni)
      acc[mi][ni] = (floatx4){0.f, 0.f, 0.f, 0.f};

#pragma unroll
  for (int ks = 0; ks < 4; ++ks) {
    short8 a[4], b[4];
    int cs = (ks * 4 + quad) ^ mr;   // (row&15)==mr for all frag rows
#pragma unroll
    for (int mi = 0; mi < 4; ++mi)
      a[mi] = *(const short8*)&As[wm * 64 + mi * 16 + mr][cs * 8];
#pragma unroll
    for (int ni = 0; ni < 4; ++ni)
      b[ni] = *(const short8*)&Ws[wn * 64 + ni * 16 + mr][cs * 8];
#pragma unroll
    for (int mi = 0; mi < 4; ++mi)
#pragma unroll
      for (int ni = 0; ni < 4; ++ni)
        acc[mi][ni] = __builtin_amdgcn_mfma_f32_16x16x32_bf16(
            a[mi], b[ni], acc[mi][ni], 0, 0, 0);
  }

  // ---- epilogue: C/D layout col=lane&15, row=quad*4+reg ----
#pragma unroll
  for (int mi = 0; mi < 4; ++mi) {
#pragma unroll
    for (int ni = 0; ni < 4; ++ni) {
      int col = wn * 64 + ni * 16 + mr;
      int rbase = row0 + wm * 64 + mi * 16 + quad * 4;
      float bv = (bias != nullptr) ? bias[col] : 0.0f;
#pragma unroll
      for (int rg = 0; rg < 4; ++rg) {
        int rr = rbase + rg;
        if (rr < NN) {
          size_t idx = (size_t)rr * DD + col;
          float v = acc[mi][ni][rg] + bv;
          if (flags & 1) v += out[idx];
          if (flags & 2) v = fmaxf(v, 0.0f);
          out[idx] = v;
        }
      }
    }
  }
}

// ---------------------------------------------------------------------------
extern "C" void kernel_launch(void* const* d_in, const int* in_sizes, int n_in,
                              void* d_out, int out_size, void* d_ws, size_t ws_size,
                              hipStream_t stream) {
  const float* x       = (const float*)d_in[0];
  const int*   ei      = (const int*)d_in[1];   // [2*E] src rows then dst rows
  const int*   et      = (const int*)d_in[2];   // [E]
  const float* rel_w1  = (const float*)d_in[3]; // [8][128][128]
  const float* root_w1 = (const float*)d_in[4];
  const float* b1      = (const float*)d_in[5];
  const float* rel_w2  = (const float*)d_in[6];
  const float* root_w2 = (const float*)d_in[7];
  const float* b2      = (const float*)d_in[8];
  float* out = (float*)d_out;

  // workspace layout
  char* ws = (char*)d_ws;
  const size_t AGG_B  = (size_t)NN * DD * sizeof(float);   // 51.2 MB
  const size_t H1_B   = AGG_B;                             // 51.2 MB
  const size_t CNT_B  = (size_t)RR * NN * sizeof(float);   // 3.2 MB
  const size_t BCNT_B = 256;
  float* agg  = (float*)(ws);
  float* h1   = (float*)(ws + AGG_B);
  float* cnt  = (float*)(ws + AGG_B + H1_B);
  int*   bcnt = (int*)  (ws + AGG_B + H1_B + CNT_B);
  int2*  ebuf = (int2*) (ws + AGG_B + H1_B + CNT_B + BCNT_B);

  hipMemsetAsync(agg, 0, AGG_B, stream);
  hipMemsetAsync(cnt, 0, CNT_B, stream);
  hipMemsetAsync(bcnt, 0, BCNT_B, stream);

  bucket_kernel<<<EE / 256, 256, 0, stream>>>(ei, et, ebuf, bcnt, cnt);

  const int GEMM_GRID = (NN + 127) / 128;  // 782
  const int SCAT_GRID = 2048;

  // ---- layer 1 ----
  gemm_pass<<<GEMM_GRID, 256, 0, stream>>>(x, nullptr, nullptr, root_w1, b1, h1, 0);
  for (int r = 0; r < RR; ++r) {
    scatter_kernel<<<SCAT_GRID, 256, 0, stream>>>(ebuf, bcnt, r, (const float4*)x, agg);
    int flags = 1 | 4 | ((r == RR - 1) ? 2 : 0);
    gemm_pass<<<GEMM_GRID, 256, 0, stream>>>(agg, agg, cnt + (size_t)r * NN,
                                             rel_w1 + (size_t)r * DD * DD,
                                             nullptr, h1, flags);
  }

  // ---- layer 2 ----
  gemm_pass<<<GEMM_GRID, 256, 0, stream>>>(h1, nullptr, nullptr, root_w2, b2, out, 0);
  for (int r = 0; r < RR; ++r) {
    scatter_kernel<<<SCAT_GRID, 256, 0, stream>>>(ebuf, bcnt, r, (const float4*)h1, agg);
    int flags = 1 | 4 | ((r == RR - 1) ? 2 : 0);
    gemm_pass<<<GEMM_GRID, 256, 0, stream>>>(agg, agg, cnt + (size_t)r * NN,
                                             rel_w2 + (size_t)r * DD * DD,
                                             nullptr, out, flags);
  }
}

// Round 2
// 3893.543 us; speedup vs baseline: 1.2209x; 1.2209x over previous
//
#include <hip/hip_runtime.h>

#define NN 100000
#define EE 640000
#define DD 128
#define RR 8
#define NB 2500   // EE / 256

typedef __attribute__((ext_vector_type(8))) short short8;
typedef __attribute__((ext_vector_type(4))) float floatx4;

__device__ __forceinline__ unsigned short f2bf(float f) {
  unsigned int u = __float_as_uint(f);
  u += 0x7FFFu + ((u >> 16) & 1u);   // round-to-nearest-even
  return (unsigned short)(u >> 16);
}

// ---------------------------------------------------------------------------
// Phase 1: per-block per-relation counts (ballot-aggregated, LDS only)
// ---------------------------------------------------------------------------
__global__ __launch_bounds__(256) void count_kernel(
    const int* __restrict__ et, int* __restrict__ blkcnt)
{
  __shared__ int lcnt[RR];
  if (threadIdx.x < RR) lcnt[threadIdx.x] = 0;
  __syncthreads();
  int e = blockIdx.x * 256 + threadIdx.x;   // grid is exact (EE % 256 == 0)
  int t = et[e];
  int lane = threadIdx.x & 63;
#pragma unroll
  for (int r = 0; r < RR; ++r) {
    unsigned long long m = __ballot(t == r);
    if (t == r && lane == (int)__ffsll(m) - 1)
      atomicAdd(&lcnt[r], (int)__popcll(m));
  }
  __syncthreads();
  if (threadIdx.x < RR) blkcnt[threadIdx.x * NB + blockIdx.x] = lcnt[threadIdx.x];
}

// ---------------------------------------------------------------------------
// Phase 2: exclusive prefix over blocks, per relation. 1 block, 8 waves.
// Wave w handles relation w: 64 lanes x 40-entry chunks, shfl-scan of chunk sums.
// ---------------------------------------------------------------------------
__global__ __launch_bounds__(512) void prefix_kernel(
    const int* __restrict__ blkcnt, int* __restrict__ blkbase,
    int* __restrict__ bcnt)
{
  const int CH = 40;                       // 64*40 = 2560 >= NB
  int r = threadIdx.x >> 6, lane = threadIdx.x & 63;
  int b0 = lane * CH;
  int s = 0;
#pragma unroll
  for (int i = 0; i < CH; ++i) {
    int b = b0 + i;
    if (b < NB) s += blkcnt[r * NB + b];
  }
  int inc = s;
  for (int d = 1; d < 64; d <<= 1) {
    int o = __shfl_up(inc, d, 64);
    if (lane >= d) inc += o;
  }
  int running = inc - s;                   // exclusive chunk base
#pragma unroll
  for (int i = 0; i < CH; ++i) {
    int b = b0 + i;
    if (b < NB) {
      blkbase[r * NB + b] = running;
      running += blkcnt[r * NB + b];
    }
  }
  if (lane == 63) bcnt[r] = inc;           // relation total
}

// ---------------------------------------------------------------------------
// Phase 3: place edges into relation buckets (unique slots, no global rank
// atomics) + per-(rel,dst) degree counts (scattered atomics, low contention)
// ---------------------------------------------------------------------------
__global__ __launch_bounds__(256) void place_kernel(
    const int* __restrict__ ei, const int* __restrict__ et,
    const int* __restrict__ blkbase,
    int2* __restrict__ ebuf, float* __restrict__ cnt)
{
  __shared__ int lcnt[RR];
  if (threadIdx.x < RR) lcnt[threadIdx.x] = 0;
  __syncthreads();
  int e = blockIdx.x * 256 + threadIdx.x;
  int t = et[e];
  int src = ei[e], dst = ei[EE + e];
  int lane = threadIdx.x & 63;
  unsigned long long lanebit = 1ull << lane;
#pragma unroll
  for (int r = 0; r < RR; ++r) {
    unsigned long long m = __ballot(t == r);
    if (t == r) {
      int rank = (int)__popcll(m & (lanebit - 1ull));
      int leader = (int)__ffsll(m) - 1;
      int base = 0;
      if (lane == leader) base = atomicAdd(&lcnt[r], (int)__popcll(m));
      base = __shfl(base, leader, 64);
      int slot = blkbase[r * NB + blockIdx.x] + base + rank;
      ebuf[(size_t)r * EE + slot] = make_int2(src, dst);
      atomicAdd(&cnt[(size_t)r * NN + dst], 1.0f);
    }
  }
}

// ---------------------------------------------------------------------------
// Scatter-add X[src] rows into agg[dst] for one relation. 32 lanes per edge,
// float4 gather + 4 fp32 atomics per lane.
// ---------------------------------------------------------------------------
__global__ __launch_bounds__(256) void scatter_kernel(
    const int2* __restrict__ ebuf, const int* __restrict__ bcnt, int r,
    const float4* __restrict__ X, float* agg)
{
  int n = bcnt[r];
  const int2* e = ebuf + (size_t)r * EE;
  int g = (blockIdx.x * 256 + threadIdx.x) >> 5;
  int lane = threadIdx.x & 31;
  int stride = (gridDim.x * 256) >> 5;
  for (int i = g; i < n; i += stride) {
    int2 ed = e[i];
    float4 v = X[(size_t)ed.x * 32 + lane];
    float* d = agg + (size_t)ed.y * DD + lane * 4;
    atomicAdd(d + 0, v.x);
    atomicAdd(d + 1, v.y);
    atomicAdd(d + 2, v.z);
    atomicAdd(d + 3, v.w);
  }
}

// ---------------------------------------------------------------------------
// GEMM pass: out[128-row tile] (+)= (A * rowscale) @ W  (+bias) (relu)
// BM=128, BN=128, K=128 (whole). bf16 MFMA 16x16x32, 4 waves = 2x2 quadrants.
// XOR-swizzled LDS (16B chunk granularity), exactly 64KB LDS.
// flags: 1=accumulate into out, 2=relu, 4=zero A region after reading.
// ---------------------------------------------------------------------------
__global__ __launch_bounds__(256, 2) void gemm_pass(
    const float* A, float* Azero,
    const float* scale,                // per-row count (or null): s = 1/max(c,1)
    const float* __restrict__ W,       // [K=128][N=128] row-major f32
    const float* __restrict__ bias,    // [128] or null
    float* out, int flags)
{
  __shared__ unsigned short As[128][128];
  __shared__ unsigned short Ws[128][128];
  const int tid = threadIdx.x;
  const int row0 = blockIdx.x * 128;

  // ---- stage A (f32 -> bf16, scaled, swizzled) ----
  {
    int row = tid >> 1, half = tid & 1;
    int grow = row0 + row;
    float s = 1.0f;
    if (scale != nullptr && grow < NN) s = 1.0f / fmaxf(scale[grow], 1.0f);
    const float4* A4 = (const float4*)A;
#pragma unroll
    for (int i = 0; i < 8; ++i) {
      int c = half * 8 + i;  // 16B chunk index (8 bf16)
      float4 v0 = make_float4(0.f, 0.f, 0.f, 0.f), v1 = v0;
      if (grow < NN) {
        v0 = A4[(size_t)grow * 32 + c * 2];
        v1 = A4[(size_t)grow * 32 + c * 2 + 1];
      }
      short8 pk;
      pk[0] = (short)f2bf(v0.x * s); pk[1] = (short)f2bf(v0.y * s);
      pk[2] = (short)f2bf(v0.z * s); pk[3] = (short)f2bf(v0.w * s);
      pk[4] = (short)f2bf(v1.x * s); pk[5] = (short)f2bf(v1.y * s);
      pk[6] = (short)f2bf(v1.z * s); pk[7] = (short)f2bf(v1.w * s);
      int cs = c ^ (row & 15);
      *(short8*)&As[row][cs * 8] = pk;
    }
    if ((flags & 4) && grow < NN) {
      float4* Az = (float4*)Azero;
      float4 z = make_float4(0.f, 0.f, 0.f, 0.f);
#pragma unroll
      for (int i = 0; i < 16; ++i) Az[(size_t)grow * 32 + half * 16 + i] = z;
    }
  }

  // ---- stage W transposed: Ws[n][k] (f32 -> bf16, swizzled) ----
  {
    int n = tid >> 1, khalf = tid & 1;
#pragma unroll
    for (int ci = 0; ci < 8; ++ci) {
      short8 pk;
#pragma unroll
      for (int j = 0; j < 8; ++j) {
        int k = khalf * 64 + ci * 8 + j;
        pk[j] = (short)f2bf(W[k * DD + n]);
      }
      int c = khalf * 8 + ci;
      int cs = c ^ (n & 15);
      *(short8*)&Ws[n][cs * 8] = pk;
    }
  }
  __syncthreads();

  // ---- compute: each wave a 64x64 quadrant ----
  const int wave = tid >> 6, lane = tid & 63;
  const int quad = lane >> 4, mr = lane & 15;
  const int wm = wave >> 1, wn = wave & 1;

  floatx4 acc[4][4];
#pragma unroll
  for (int mi = 0; mi < 4; ++mi)
#pragma unroll
    for (int ni = 0; ni < 4; ++ni)
      acc[mi][ni] = (floatx4){0.f, 0.f, 0.f, 0.f};

#pragma unroll
  for (int ks = 0; ks < 4; ++ks) {
    short8 a[4], b[4];
    int cs = (ks * 4 + quad) ^ mr;
#pragma unroll
    for (int mi = 0; mi < 4; ++mi)
      a[mi] = *(const short8*)&As[wm * 64 + mi * 16 + mr][cs * 8];
#pragma unroll
    for (int ni = 0; ni < 4; ++ni)
      b[ni] = *(const short8*)&Ws[wn * 64 + ni * 16 + mr][cs * 8];
#pragma unroll
    for (int mi = 0; mi < 4; ++mi)
#pragma unroll
      for (int ni = 0; ni < 4; ++ni)
        acc[mi][ni] = __builtin_amdgcn_mfma_f32_16x16x32_bf16(
            a[mi], b[ni], acc[mi][ni], 0, 0, 0);
  }

  // ---- epilogue: C/D layout col=lane&15, row=quad*4+reg ----
#pragma unroll
  for (int mi = 0; mi < 4; ++mi) {
#pragma unroll
    for (int ni = 0; ni < 4; ++ni) {
      int col = wn * 64 + ni * 16 + mr;
      int rbase = row0 + wm * 64 + mi * 16 + quad * 4;
      float bv = (bias != nullptr) ? bias[col] : 0.0f;
#pragma unroll
      for (int rg = 0; rg < 4; ++rg) {
        int rr = rbase + rg;
        if (rr < NN) {
          size_t idx = (size_t)rr * DD + col;
          float v = acc[mi][ni][rg] + bv;
          if (flags & 1) v += out[idx];
          if (flags & 2) v = fmaxf(v, 0.0f);
          out[idx] = v;
        }
      }
    }
  }
}

// ---------------------------------------------------------------------------
extern "C" void kernel_launch(void* const* d_in, const int* in_sizes, int n_in,
                              void* d_out, int out_size, void* d_ws, size_t ws_size,
                              hipStream_t stream) {
  const float* x       = (const float*)d_in[0];
  const int*   ei      = (const int*)d_in[1];
  const int*   et      = (const int*)d_in[2];
  const float* rel_w1  = (const float*)d_in[3];
  const float* root_w1 = (const float*)d_in[4];
  const float* b1      = (const float*)d_in[5];
  const float* rel_w2  = (const float*)d_in[6];
  const float* root_w2 = (const float*)d_in[7];
  const float* b2      = (const float*)d_in[8];
  float* out = (float*)d_out;

  // workspace layout
  char* ws = (char*)d_ws;
  const size_t AGG_B  = (size_t)NN * DD * sizeof(float);   // 51.2 MB
  const size_t H1_B   = AGG_B;                             // 51.2 MB
  const size_t CNT_B  = (size_t)RR * NN * sizeof(float);   // 3.2 MB
  const size_t BCNT_B = 256;
  const size_t EBUF_B = (size_t)RR * EE * sizeof(int2);    // 41 MB
  float* agg    = (float*)(ws);
  float* h1     = (float*)(ws + AGG_B);
  float* cnt    = (float*)(ws + AGG_B + H1_B);
  int*   bcnt   = (int*)  (ws + AGG_B + H1_B + CNT_B);
  int2*  ebuf   = (int2*) (ws + AGG_B + H1_B + CNT_B + BCNT_B);
  int*   blkcnt = (int*)  (ws + AGG_B + H1_B + CNT_B + BCNT_B + EBUF_B);
  int*   blkbase= blkcnt + RR * NB;

  hipMemsetAsync(agg, 0, AGG_B, stream);
  hipMemsetAsync(cnt, 0, CNT_B, stream);

  count_kernel <<<NB, 256, 0, stream>>>(et, blkcnt);
  prefix_kernel<<<1, 512, 0, stream>>>(blkcnt, blkbase, bcnt);
  place_kernel <<<NB, 256, 0, stream>>>(ei, et, blkbase, ebuf, cnt);

  const int GEMM_GRID = (NN + 127) / 128;  // 782
  const int SCAT_GRID = 2048;

  // ---- layer 1 ----
  gemm_pass<<<GEMM_GRID, 256, 0, stream>>>(x, nullptr, nullptr, root_w1, b1, h1, 0);
  for (int r = 0; r < RR; ++r) {
    scatter_kernel<<<SCAT_GRID, 256, 0, stream>>>(ebuf, bcnt, r, (const float4*)x, agg);
    int flags = 1 | 4 | ((r == RR - 1) ? 2 : 0);
    gemm_pass<<<GEMM_GRID, 256, 0, stream>>>(agg, agg, cnt + (size_t)r * NN,
                                             rel_w1 + (size_t)r * DD * DD,
                                             nullptr, h1, flags);
  }

  // ---- layer 2 ----
  gemm_pass<<<GEMM_GRID, 256, 0, stream>>>(h1, nullptr, nullptr, root_w2, b2, out, 0);
  for (int r = 0; r < RR; ++r) {
    scatter_kernel<<<SCAT_GRID, 256, 0, stream>>>(ebuf, bcnt, r, (const float4*)h1, agg);
    int flags = 1 | 4 | ((r == RR - 1) ? 2 : 0);
    gemm_pass<<<GEMM_GRID, 256, 0, stream>>>(agg, agg, cnt + (size_t)r * NN,
                                             rel_w2 + (size_t)r * DD * DD,
                                             nullptr, out, flags);
  }
}

// Round 3
// 509.865 us; speedup vs baseline: 9.3231x; 7.6364x over previous
//
#include <hip/hip_runtime.h>
#include <hip/hip_bf16.h>

#define NN 100000
#define EE 640000
#define DD 128
#define RR 8
#define K_TOT (NN * RR)          // 800000 CSR keys: key = dst*8 + r
#define NSB 196                  // ceil(K_TOT / 4096) scan blocks

typedef __attribute__((ext_vector_type(8))) short short8;
typedef __attribute__((ext_vector_type(4))) float floatx4;
typedef __attribute__((ext_vector_type(4))) unsigned int uint4v;

__device__ __forceinline__ unsigned short f2bf(float f) {
  unsigned int u = __float_as_uint(f);
  u += 0x7FFFu + ((u >> 16) & 1u);   // RNE
  return (unsigned short)(u >> 16);
}
__device__ __forceinline__ float bf2f(short s) {
  return __uint_as_float(((unsigned int)(unsigned short)s) << 16);
}
__device__ __forceinline__ unsigned int pk2bf(float a, float b) {
  __hip_bfloat162 h = __float22bfloat162_rn(make_float2(a, b));
  unsigned int u;
  __builtin_memcpy(&u, &h, 4);
  return u;
}

// ---------------------------------------------------------------------------
// x (fp32) -> Xb (bf16), 8 elems/thread
// ---------------------------------------------------------------------------
__global__ __launch_bounds__(256) void xb_prep(
    const float* __restrict__ x, unsigned short* __restrict__ xb)
{
  size_t i = ((size_t)blockIdx.x * 256 + threadIdx.x) * 8;
  const float4* x4 = (const float4*)(x + i);
  float4 v0 = x4[0], v1 = x4[1];
  uint4v w;
  w[0] = pk2bf(v0.x, v0.y); w[1] = pk2bf(v0.z, v0.w);
  w[2] = pk2bf(v1.x, v1.y); w[3] = pk2bf(v1.z, v1.w);
  *(uint4v*)(xb + i) = w;
}

// ---------------------------------------------------------------------------
// Weights: Wt[r][n][k] = bf16(W_r[k][n]); r=8 is root_w. 147456 elems exact.
// ---------------------------------------------------------------------------
__global__ __launch_bounds__(256) void w_prep(
    const float* __restrict__ relw, const float* __restrict__ rootw,
    unsigned short* __restrict__ wt)
{
  int id = blockIdx.x * 256 + threadIdx.x;       // [0, 9*128*128)
  int r = id >> 14, rem = id & 16383;
  int n = rem >> 7, k = rem & 127;
  float v = (r < RR) ? relw[((size_t)r * DD + k) * DD + n] : rootw[(size_t)k * DD + n];
  wt[id] = f2bf(v);
}

// ---------------------------------------------------------------------------
// CSR build: count -> scan(a,b,c) -> place.  key = dst*8 + r
// ---------------------------------------------------------------------------
__global__ __launch_bounds__(256) void count_kernel(
    const int* __restrict__ ei, const int* __restrict__ et, int* __restrict__ cnt)
{
  int e = blockIdx.x * 256 + threadIdx.x;
  atomicAdd(&cnt[ei[EE + e] * RR + et[e]], 1);
}

__global__ __launch_bounds__(256) void scan_a(
    const int4* __restrict__ cnt4, int* __restrict__ bsum)
{
  int t = threadIdx.x;
  int s = 0;
#pragma unroll
  for (int i = 0; i < 4; ++i) {
    int idx = blockIdx.x * 1024 + i * 256 + t;
    if (idx < K_TOT / 4) { int4 v = cnt4[idx]; s += v.x + v.y + v.z + v.w; }
  }
  __shared__ int wsum[4];
  for (int d = 32; d; d >>= 1) s += __shfl_xor(s, d, 64);
  if ((t & 63) == 0) wsum[t >> 6] = s;
  __syncthreads();
  if (t == 0) bsum[blockIdx.x] = wsum[0] + wsum[1] + wsum[2] + wsum[3];
}

__global__ void scan_b(const int* __restrict__ bsum, int* __restrict__ bbase)
{
  int lane = threadIdx.x;                         // 64 threads
  int v[4]; int s = 0;
#pragma unroll
  for (int i = 0; i < 4; ++i) {
    int idx = lane * 4 + i;
    v[i] = (idx < NSB) ? bsum[idx] : 0; s += v[i];
  }
  int inc = s;
  for (int d = 1; d < 64; d <<= 1) {
    int o = __shfl_up(inc, d, 64);
    if (lane >= d) inc += o;
  }
  int running = inc - s;
#pragma unroll
  for (int i = 0; i < 4; ++i) {
    int idx = lane * 4 + i;
    if (idx < NSB) { bbase[idx] = running; running += v[i]; }
  }
}

__global__ __launch_bounds__(256) void scan_c(
    const int* __restrict__ cnt, const int* __restrict__ bbase,
    int* __restrict__ rowptr, int* __restrict__ rowfill)
{
  int t = threadIdx.x;
  int base = blockIdx.x * 4096 + t * 16;
  int v[16]; int s = 0;
#pragma unroll
  for (int i = 0; i < 16; ++i) {
    int idx = base + i;
    v[i] = (idx < K_TOT) ? cnt[idx] : 0; s += v[i];
  }
  int lane = t & 63, wid = t >> 6;
  int inc = s;
  for (int d = 1; d < 64; d <<= 1) {
    int o = __shfl_up(inc, d, 64);
    if (lane >= d) inc += o;
  }
  __shared__ int wsum[4];
  if (lane == 63) wsum[wid] = inc;
  __syncthreads();
  int wb = 0;
  for (int w = 0; w < wid; ++w) wb += wsum[w];
  int running = bbase[blockIdx.x] + wb + (inc - s);
#pragma unroll
  for (int i = 0; i < 16; ++i) {
    int idx = base + i;
    if (idx < K_TOT) { rowptr[idx] = running; rowfill[idx] = running; running += v[i]; }
  }
  if (blockIdx.x == 0 && t == 0) rowptr[K_TOT] = EE;
}

__global__ __launch_bounds__(256) void place_kernel(
    const int* __restrict__ ei, const int* __restrict__ et,
    int* __restrict__ rowfill, int* __restrict__ esrc)
{
  int e = blockIdx.x * 256 + threadIdx.x;
  int slot = atomicAdd(&rowfill[ei[EE + e] * RR + et[e]], 1);
  esrc[slot] = ei[e];
}

// ---------------------------------------------------------------------------
// Fused RGCN layer: per 128-dst block, 9 rounds (8 relations + root):
//   round r<8 : As[row] = (1/max(len,1)) * sum_{e in CSR[dst*8+r]} Xb[src]  (bf16)
//   round r=8 : As[row] = Xb[dst]
//   MFMA-accumulate As @ Wt[r] into acc[4][4] (bf16 16x16x32, 4 waves 2x2).
// Epilogue: +bias, relu, store bf16 (mid layer) or fp32 (final).
// ---------------------------------------------------------------------------
__global__ __launch_bounds__(256, 2) void fused_layer(
    const unsigned short* __restrict__ Xb,   // [NN][128] bf16
    const int* __restrict__ rowptr,          // [K_TOT+1]
    const int* __restrict__ esrc,            // [EE]
    const unsigned short* __restrict__ Wt,   // [9][128][128] bf16 [r][n][k]
    const float* __restrict__ bias,          // [128]
    void* __restrict__ outp, int out_bf16)
{
  __shared__ unsigned short As[128][128];
  __shared__ unsigned short Ws[128][128];
  const int tid = threadIdx.x;
  const int row0 = blockIdx.x * 128;
  const int wave = tid >> 6, lane = tid & 63;
  const int quad = lane >> 4, mr = lane & 15;
  const int wm = wave >> 1, wn = wave & 1;

  floatx4 acc[4][4];
#pragma unroll
  for (int mi = 0; mi < 4; ++mi)
#pragma unroll
    for (int ni = 0; ni < 4; ++ni)
      acc[mi][ni] = (floatx4){0.f, 0.f, 0.f, 0.f};

  for (int r = 0; r < 9; ++r) {
    // ---- stage Ws (bf16 prepacked, [n][k], swizzled) ----
    {
      int n = tid >> 1, khalf = tid & 1;
      const unsigned short* wrow = Wt + ((size_t)r * 128 + n) * 128;
#pragma unroll
      for (int ci = 0; ci < 8; ++ci) {
        int c = khalf * 8 + ci;
        short8 pk = *(const short8*)(wrow + c * 8);
        int cs = c ^ (n & 15);
        *(short8*)&Ws[n][cs * 8] = pk;
      }
    }
    // ---- stage As ----
    if (r < RR) {
      int q = tid & 3;             // column quarter (32 bf16)
#pragma unroll
      for (int sub = 0; sub < 2; ++sub) {
        int row = sub * 64 + (tid >> 2);
        int dst = row0 + row;
        float sum[32];
#pragma unroll
        for (int i = 0; i < 32; ++i) sum[i] = 0.f;
        if (dst < NN) {
          int k = dst * RR + r;
          int beg = rowptr[k], end = rowptr[k + 1];
          float sc = 1.0f / (float)max(end - beg, 1);
          for (int e = beg; e < end; ++e) {
            const unsigned short* xr = Xb + (size_t)esrc[e] * DD + q * 32;
#pragma unroll
            for (int c4 = 0; c4 < 4; ++c4) {
              short8 v = *(const short8*)(xr + c4 * 8);
#pragma unroll
              for (int j = 0; j < 8; ++j) sum[c4 * 8 + j] += bf2f(v[j]);
            }
          }
#pragma unroll
          for (int i = 0; i < 32; ++i) sum[i] *= sc;
        }
#pragma unroll
        for (int c4 = 0; c4 < 4; ++c4) {
          uint4v w;
          w[0] = pk2bf(sum[c4 * 8 + 0], sum[c4 * 8 + 1]);
          w[1] = pk2bf(sum[c4 * 8 + 2], sum[c4 * 8 + 3]);
          w[2] = pk2bf(sum[c4 * 8 + 4], sum[c4 * 8 + 5]);
          w[3] = pk2bf(sum[c4 * 8 + 6], sum[c4 * 8 + 7]);
          int c = q * 4 + c4;
          int cs = c ^ (row & 15);
          *(uint4v*)&As[row][cs * 8] = w;
        }
      }
    } else {                       // root round: As[row] = Xb[dst]
      int row = tid >> 1, half = tid & 1;
      int dst = row0 + row;
#pragma unroll
      for (int i = 0; i < 8; ++i) {
        int c = half * 8 + i;
        short8 pk = (short8)0;
        if (dst < NN) pk = *(const short8*)(Xb + (size_t)dst * DD + c * 8);
        int cs = c ^ (row & 15);
        *(short8*)&As[row][cs * 8] = pk;
      }
    }
    __syncthreads();
    // ---- MFMA ----
#pragma unroll
    for (int ks = 0; ks < 4; ++ks) {
      short8 a[4], b[4];
      int cs = (ks * 4 + quad) ^ mr;
#pragma unroll
      for (int mi = 0; mi < 4; ++mi)
        a[mi] = *(const short8*)&As[wm * 64 + mi * 16 + mr][cs * 8];
#pragma unroll
      for (int ni = 0; ni < 4; ++ni)
        b[ni] = *(const short8*)&Ws[wn * 64 + ni * 16 + mr][cs * 8];
#pragma unroll
      for (int mi = 0; mi < 4; ++mi)
#pragma unroll
        for (int ni = 0; ni < 4; ++ni)
          acc[mi][ni] = __builtin_amdgcn_mfma_f32_16x16x32_bf16(
              a[mi], b[ni], acc[mi][ni], 0, 0, 0);
    }
    __syncthreads();
  }

  // ---- epilogue: C/D layout col=lane&15, row=quad*4+reg ----
#pragma unroll
  for (int mi = 0; mi < 4; ++mi) {
#pragma unroll
    for (int ni = 0; ni < 4; ++ni) {
      int col = wn * 64 + ni * 16 + mr;
      int rbase = row0 + wm * 64 + mi * 16 + quad * 4;
      float bv = bias[col];
#pragma unroll
      for (int rg = 0; rg < 4; ++rg) {
        int rr = rbase + rg;
        if (rr < NN) {
          float v = fmaxf(acc[mi][ni][rg] + bv, 0.0f);
          size_t idx = (size_t)rr * DD + col;
          if (out_bf16) ((unsigned short*)outp)[idx] = f2bf(v);
          else          ((float*)outp)[idx] = v;
        }
      }
    }
  }
}

// ---------------------------------------------------------------------------
extern "C" void kernel_launch(void* const* d_in, const int* in_sizes, int n_in,
                              void* d_out, int out_size, void* d_ws, size_t ws_size,
                              hipStream_t stream) {
  const float* x       = (const float*)d_in[0];
  const int*   ei      = (const int*)d_in[1];
  const int*   et      = (const int*)d_in[2];
  const float* rel_w1  = (const float*)d_in[3];
  const float* root_w1 = (const float*)d_in[4];
  const float* b1      = (const float*)d_in[5];
  const float* rel_w2  = (const float*)d_in[6];
  const float* root_w2 = (const float*)d_in[7];
  const float* b2      = (const float*)d_in[8];
  float* out = (float*)d_out;

  // workspace layout (all 256B-aligned)
  char* ws = (char*)d_ws;
  size_t off = 0;
  auto alloc = [&](size_t bytes) { char* p = ws + off; off = (off + bytes + 255) & ~(size_t)255; return p; };
  unsigned short* Xb      = (unsigned short*)alloc((size_t)NN * DD * 2);       // 25.6 MB
  unsigned short* h1      = (unsigned short*)alloc((size_t)NN * DD * 2);       // 25.6 MB
  unsigned short* Wt1     = (unsigned short*)alloc((size_t)9 * DD * DD * 2);
  unsigned short* Wt2     = (unsigned short*)alloc((size_t)9 * DD * DD * 2);
  int*            cnt32   = (int*)alloc((size_t)K_TOT * 4);                    // 3.2 MB
  int*            rowptr  = (int*)alloc((size_t)(K_TOT + 1) * 4);
  int*            rowfill = (int*)alloc((size_t)K_TOT * 4);
  int*            esrc    = (int*)alloc((size_t)EE * 4);                       // 2.56 MB
  int*            bsum    = (int*)alloc((size_t)NSB * 4);
  int*            bbase   = (int*)alloc((size_t)NSB * 4);

  hipMemsetAsync(cnt32, 0, (size_t)K_TOT * 4, stream);

  xb_prep<<<(NN * DD) / (256 * 8), 256, 0, stream>>>(x, Xb);        // 6250 blocks
  w_prep<<<(9 * DD * DD) / 256, 256, 0, stream>>>(rel_w1, root_w1, Wt1);
  w_prep<<<(9 * DD * DD) / 256, 256, 0, stream>>>(rel_w2, root_w2, Wt2);

  count_kernel<<<EE / 256, 256, 0, stream>>>(ei, et, cnt32);
  scan_a<<<NSB, 256, 0, stream>>>((const int4*)cnt32, bsum);
  scan_b<<<1, 64, 0, stream>>>(bsum, bbase);
  scan_c<<<NSB, 256, 0, stream>>>(cnt32, bbase, rowptr, rowfill);
  place_kernel<<<EE / 256, 256, 0, stream>>>(ei, et, rowfill, esrc);

  const int GEMM_GRID = (NN + 127) / 128;  // 782
  fused_layer<<<GEMM_GRID, 256, 0, stream>>>(Xb, rowptr, esrc, Wt1, b1, h1, 1);
  fused_layer<<<GEMM_GRID, 256, 0, stream>>>(h1, rowptr, esrc, Wt2, b2, out, 0);
}